// Round 12
// baseline (218.873 us; speedup 1.0000x reference)
//
#include <hip/hip_runtime.h>
#include <hip/hip_bf16.h>
#include <math.h>

#define GRID_N 24
#define NV 576
#define NT 8192
#define DK 4096
#define TOPK 16
#define LDT 68       // padded leading dim for fp32 [k][m] LDS tiles (fallback scos kernel)
#define DELTA 0.005f // Gaussian inputs: hi*hi dot error std ~2.4e-5, max ~1.3e-4 -> 38x margin
#define WCAP 32768

typedef __bf16 bf16x8 __attribute__((ext_vector_type(8)));
typedef __bf16 bf16x4 __attribute__((ext_vector_type(4)));
typedef float  f32x4  __attribute__((ext_vector_type(4)));

__device__ __forceinline__ unsigned fkey(float f){
  unsigned u = __float_as_uint(f);
  return (u & 0x80000000u) ? ~u : (u | 0x80000000u);
}
__device__ __forceinline__ float fkey_inv(unsigned u){
  unsigned b = (u & 0x80000000u) ? (u & 0x7fffffffu) : ~u;
  return __uint_as_float(b);
}

__device__ __forceinline__ void gload_lds16(const void* g, void* l){
  __builtin_amdgcn_global_load_lds((const __attribute__((address_space(1))) unsigned*)g,
                                   (__attribute__((address_space(3))) unsigned*)l, 16, 0, 0);
}

// ---------------- prep_all: T-norm+bf16 | V-norm+hi/lo split | mask expand + zero-init ----------------
__global__ __launch_bounds__(256) void prep_all(const float* __restrict__ V,
                                                const float* __restrict__ T,
                                                const unsigned char* __restrict__ mraw,
                                                __bf16* __restrict__ Vh,
                                                __bf16* __restrict__ Vl,
                                                __bf16* __restrict__ Th,
                                                float* __restrict__ invv,
                                                float* __restrict__ invt,
                                                int* __restrict__ mv,
                                                unsigned* __restrict__ skey,
                                                unsigned* __restrict__ skeyx,
                                                int* __restrict__ wcnt){
  int bid = blockIdx.x;
  int tid = threadIdx.x;
  if(bid < NT){
    int r = bid;
    const float4* p = (const float4*)(T + (size_t)r * DK);
    __bf16* o = Th + (size_t)r * DK;
    float s = 0.f;
    for(int c = tid; c < DK/4; c += 256){
      float4 v = p[c];
      s += v.x*v.x + v.y*v.y + v.z*v.z + v.w*v.w;
      bf16x4 h = { (__bf16)v.x, (__bf16)v.y, (__bf16)v.z, (__bf16)v.w };
      *(bf16x4*)(o + c*4) = h;
    }
    for(int d = 32; d > 0; d >>= 1) s += __shfl_down(s, d);
    __shared__ float r4[4];
    if((tid & 63) == 0) r4[tid >> 6] = s;
    __syncthreads();
    if(tid == 0){
      float t = r4[0] + r4[1] + r4[2] + r4[3];
      invt[r] = 1.0f / fmaxf(sqrtf(t), 1e-8f);
    }
  } else if(bid < NT + NV){
    int r = bid - NT;
    const float4* p = (const float4*)(V + (size_t)r * DK);
    __bf16* oh = Vh + (size_t)r * DK;
    __bf16* ol = Vl + (size_t)r * DK;
    float s = 0.f;
    for(int c = tid; c < DK/4; c += 256){
      float4 v = p[c];
      s += v.x*v.x + v.y*v.y + v.z*v.z + v.w*v.w;
      float f[4] = {v.x, v.y, v.z, v.w};
      bf16x4 h, l;
      #pragma unroll
      for(int q = 0; q < 4; q++){
        __bf16 hv = (__bf16)f[q];
        h[q] = hv;
        l[q] = (__bf16)(f[q] - (float)hv);
      }
      *(bf16x4*)(oh + c*4) = h;
      *(bf16x4*)(ol + c*4) = l;
    }
    for(int d = 32; d > 0; d >>= 1) s += __shfl_down(s, d);
    __shared__ float r4v[4];
    if((tid & 63) == 0) r4v[tid >> 6] = s;
    __syncthreads();
    if(tid == 0){
      float t = r4v[0] + r4v[1] + r4v[2] + r4v[3];
      invv[r] = 1.0f / fmaxf(sqrtf(t), 1e-8f);
    }
  } else {
    int mb = bid - NT - NV;
    int j = mb*256 + tid;
    if(j < NT){
      unsigned b0 = mraw[0], b1 = mraw[1], b2 = mraw[2], b3 = mraw[3];
      bool isf32 = (b0 == 0 && b1 == 0 && b2 == 0x80 && b3 == 0x3F);
      if(isf32)                 mv[j] = (((const float*)mraw)[j] != 0.0f) ? 1 : 0;
      else if((b1|b2|b3) != 0)  mv[j] = mraw[j] ? 1 : 0;
      else                      mv[j] = (((const int*)mraw)[j] != 0) ? 1 : 0;
    }
    if(mb == 0){
      for(int i = tid; i < NV; i += 256){ skey[i] = 0u; skeyx[i] = 0u; }
      if(tid == 0) *wcnt = 0;
    }
  }
}

// ---------------- fused score1 + gram ----------------
// blocks [0,576): cosm~ = Vh @ Th^T * iv*it (mask->0) + row-max atomic, XCD-swizzled.
//   T4 counted-vmcnt pipeline: stage(t+1) -> s_waitcnt vmcnt(6) (t's loads only;
//   t+1's stay in flight across the barrier) -> raw s_barrier -> MFMA -> raw
//   s_barrier (WAR guard before buf cur is re-staged). Never vmcnt(0) mid-loop.
// blocks [576,657): G = normalize(V)@normalize(V)^T 3-pass split-bf16 (single buffer).
__global__ __launch_bounds__(256) void score_gram(const __bf16* __restrict__ Vh,
                                                  const __bf16* __restrict__ Vl,
                                                  const __bf16* __restrict__ Th,
                                                  const float* __restrict__ invv,
                                                  const float* __restrict__ invt,
                                                  const int* __restrict__ mv,
                                                  float* __restrict__ cosm,
                                                  unsigned* __restrict__ skey,
                                                  float* __restrict__ G){
  __shared__ __align__(16) char lds[49152];
  int tid = threadIdx.x;
  int l = tid & 63, wid = tid >> 6;

  if(blockIdx.x < 576){
    // ================= score body =================
    __bf16* sA0 = (__bf16*)lds;             // [2][64*64]
    __bf16* sB0 = (__bf16*)(lds + 16384);   // [2][128*64]
    int m0 = (wid >> 1) * 32, n0 = (wid & 1) * 64;
    int bid = blockIdx.x;
    int orig = (bid & 7) * 72 + (bid >> 3);   // XCD x owns orig [x*72, x*72+72)
    int jt = orig / 9, it = orig % 9;          // j-major within XCD chunk
    int vbase = it * 64, tbase = jt * 128;

    // staging: 24 gload_lds16 per K-step, 6 per wave
    const __bf16* gsrc[6];
    __bf16* l0[6];
    int lstep[6];
    #pragma unroll
    for(int q = 0; q < 6; q++){
      int inst = wid*6 + q;
      int which = inst >> 3;
      int i = inst & 7;
      int r8 = i*8 + (l >> 3);
      int swz = ((l & 7) ^ (r8 & 7)) << 3;   // pre-swizzled global source, linear LDS dest
      if(which == 0){
        gsrc[q] = Vh + (size_t)(vbase + r8)*DK + swz;
        l0[q] = sA0 + i*512;  lstep[q] = 64*64;
      } else if(which == 1){
        gsrc[q] = Th + (size_t)(tbase + r8)*DK + swz;
        l0[q] = sB0 + i*512;  lstep[q] = 128*64;
      } else {
        gsrc[q] = Th + (size_t)(tbase + 64 + r8)*DK + swz;
        l0[q] = sB0 + (8+i)*512;  lstep[q] = 128*64;
      }
    }

    // hoisted per-kc LDS fragment offsets
    int aoffk[2][2], boffk[2][4];
    #pragma unroll
    for(int kc = 0; kc < 2; kc++){
      int sa = kc*4 + (l >> 4);
      #pragma unroll
      for(int fm = 0; fm < 2; fm++){
        int ra = m0 + fm*16 + (l & 15);
        aoffk[kc][fm] = ra*64 + ((sa ^ (ra & 7)) << 3);
      }
      #pragma unroll
      for(int fn = 0; fn < 4; fn++){
        int rb = n0 + fn*16 + (l & 15);
        boffk[kc][fn] = rb*64 + ((sa ^ (rb & 7)) << 3);
      }
    }

    f32x4 acc[2][4];
    #pragma unroll
    for(int i = 0; i < 2; i++)
      #pragma unroll
      for(int j = 0; j < 4; j++) acc[i][j] = (f32x4){0.f,0.f,0.f,0.f};

    // prologue: stage tile 0 into buf 0 (6 loads outstanding)
    #pragma unroll
    for(int q = 0; q < 6; q++) gload_lds16(gsrc[q], l0[q]);

    for(int t = 0; t < DK/64; t++){
      int cur = t & 1;
      if(t + 1 < DK/64){
        // issue next-tile loads: outstanding = 6 (tile t) + 6 (tile t+1)
        #pragma unroll
        for(int q = 0; q < 6; q++)
          gload_lds16(gsrc[q] + (t+1)*64, l0[q] + (cur^1)*lstep[q]);
        // wait only for tile t's loads; t+1's stay in flight across the barrier
        asm volatile("s_waitcnt vmcnt(6)" ::: "memory");
      } else {
        asm volatile("s_waitcnt vmcnt(0)" ::: "memory");
      }
      __builtin_amdgcn_s_barrier();   // buf cur fully resident for all waves
      #pragma unroll
      for(int kc = 0; kc < 2; kc++){
        bf16x8 ah[2], bh[4];
        #pragma unroll
        for(int fm = 0; fm < 2; fm++)
          ah[fm] = *(bf16x8*)(sA0 + cur*4096 + aoffk[kc][fm]);
        #pragma unroll
        for(int fn = 0; fn < 4; fn++)
          bh[fn] = *(bf16x8*)(sB0 + cur*8192 + boffk[kc][fn]);
        #pragma unroll
        for(int fm = 0; fm < 2; fm++)
          #pragma unroll
          for(int fn = 0; fn < 4; fn++)
            acc[fm][fn] = __builtin_amdgcn_mfma_f32_16x16x32_bf16(ah[fm], bh[fn], acc[fm][fn], 0, 0, 0);
      }
      __builtin_amdgcn_s_barrier();   // WAR: all waves done reading buf cur before it is re-staged
    }

    // epilogue: scale + mask, write cos~ tile, fused per-row approx max -> atomicMax(fkey)
    float* red = (float*)lds;   // alias after final drain (vmcnt(0) at t=63) + barrier
    float itc[4];
    #pragma unroll
    for(int fn = 0; fn < 4; fn++){
      int col = tbase + n0 + fn*16 + (l & 15);
      itc[fn] = (mv[col] != 0) ? invt[col] : 0.0f;
    }
    #pragma unroll
    for(int fm = 0; fm < 2; fm++){
      float rm[4];
      #pragma unroll
      for(int e = 0; e < 4; e++){
        int grow = vbase + m0 + fm*16 + ((l >> 4) << 2) + e;
        float iv = invv[grow];
        float mx = -3.402823e38f;
        #pragma unroll
        for(int fn = 0; fn < 4; fn++){
          int col = tbase + n0 + fn*16 + (l & 15);
          float val = acc[fm][fn][e] * iv * itc[fn];
          cosm[(size_t)grow*NT + col] = val;
          mx = fmaxf(mx, val);
        }
        rm[e] = mx;
      }
      #pragma unroll
      for(int d = 1; d < 16; d <<= 1){
        #pragma unroll
        for(int e = 0; e < 4; e++) rm[e] = fmaxf(rm[e], __shfl_xor(rm[e], d, 16));
      }
      if((l & 15) == 0){
        #pragma unroll
        for(int e = 0; e < 4; e++){
          int rl = m0 + fm*16 + ((l >> 4) << 2) + e;
          red[(wid & 1)*64 + rl] = rm[e];
        }
      }
    }
    __syncthreads();
    if(tid < 64){
      float m = fmaxf(red[tid], red[64 + tid]);
      atomicMax(skey + vbase + tid, fkey(m));
    }
  } else {
    // ================= gram body (single-buffered) =================
    __bf16* sAh = (__bf16*)lds;
    __bf16* sAl = (__bf16*)(lds + 8192);
    __bf16* sBh = (__bf16*)(lds + 16384);
    __bf16* sBl = (__bf16*)(lds + 24576);
    int m0 = (wid >> 1) * 32, n0 = (wid & 1) * 32;
    int gb = blockIdx.x - 576;
    int ubase = (gb / 9) * 64, ibase = (gb % 9) * 64;

    const __bf16* gsrc[8];
    __bf16* ldst[8];
    #pragma unroll
    for(int q = 0; q < 8; q++){
      int inst = wid*8 + q;
      int which = inst >> 3;
      int i = inst & 7;
      int rl = i*8 + (l >> 3);
      const __bf16* base;
      __bf16* lb;
      if(which == 0){      base = Vh + (size_t)(ubase + rl)*DK; lb = sAh + i*512; }
      else if(which == 1){ base = Vl + (size_t)(ubase + rl)*DK; lb = sAl + i*512; }
      else if(which == 2){ base = Vh + (size_t)(ibase + rl)*DK; lb = sBh + i*512; }
      else {               base = Vl + (size_t)(ibase + rl)*DK; lb = sBl + i*512; }
      int chunk_g = (l & 7) ^ (rl & 7);
      gsrc[q] = base + chunk_g*8;
      ldst[q] = lb;
    }

    int aoffk[2][2], boffk[2][2];
    #pragma unroll
    for(int kc = 0; kc < 2; kc++){
      int sa = kc*4 + (l >> 4);
      #pragma unroll
      for(int f = 0; f < 2; f++){
        int ra = m0 + f*16 + (l & 15);
        aoffk[kc][f] = ra*64 + ((sa ^ (ra & 7)) << 3);
        int rb = n0 + f*16 + (l & 15);
        boffk[kc][f] = rb*64 + ((sa ^ (rb & 7)) << 3);
      }
    }

    f32x4 acc[2][2];
    #pragma unroll
    for(int i = 0; i < 2; i++)
      #pragma unroll
      for(int j = 0; j < 2; j++) acc[i][j] = (f32x4){0.f,0.f,0.f,0.f};

    for(int k0 = 0; k0 < DK; k0 += 64){
      __syncthreads();
      #pragma unroll
      for(int q = 0; q < 8; q++) gload_lds16(gsrc[q] + k0, ldst[q]);
      __syncthreads();
      #pragma unroll
      for(int kc = 0; kc < 2; kc++){
        bf16x8 ah[2], al[2], bh[2], bl[2];
        #pragma unroll
        for(int f = 0; f < 2; f++){
          ah[f] = *(bf16x8*)(sAh + aoffk[kc][f]);
          al[f] = *(bf16x8*)(sAl + aoffk[kc][f]);
          bh[f] = *(bf16x8*)(sBh + boffk[kc][f]);
          bl[f] = *(bf16x8*)(sBl + boffk[kc][f]);
        }
        #pragma unroll
        for(int fm = 0; fm < 2; fm++)
          #pragma unroll
          for(int fn = 0; fn < 2; fn++){
            acc[fm][fn] = __builtin_amdgcn_mfma_f32_16x16x32_bf16(ah[fm], bh[fn], acc[fm][fn], 0, 0, 0);
            acc[fm][fn] = __builtin_amdgcn_mfma_f32_16x16x32_bf16(al[fm], bh[fn], acc[fm][fn], 0, 0, 0);
            acc[fm][fn] = __builtin_amdgcn_mfma_f32_16x16x32_bf16(ah[fm], bl[fn], acc[fm][fn], 0, 0, 0);
          }
      }
    }

    #pragma unroll
    for(int fm = 0; fm < 2; fm++){
      #pragma unroll
      for(int e = 0; e < 4; e++){
        int grow = ubase + m0 + fm*16 + ((l >> 4) << 2) + e;
        float su = invv[grow];
        #pragma unroll
        for(int fn = 0; fn < 2; fn++){
          int gcol = ibase + n0 + fn*16 + (l & 15);
          G[(size_t)grow*NV + gcol] = acc[fm][fn][e] * su * invv[gcol];
        }
      }
    }
  }
}

// ---------------- collect: stream cosm, emit near-max candidates to worklist ----------------
__global__ __launch_bounds__(256) void collect(const float* __restrict__ cosm,
                                               const unsigned* __restrict__ skey,
                                               int2* __restrict__ wl,
                                               int* __restrict__ wcnt){
  int i = blockIdx.x;
  float thrv = fkey_inv(skey[i]) - DELTA;
  int j0 = blockIdx.y * 2048;
  const float* row = cosm + (size_t)i*NT + j0;
  for(int k = threadIdx.x; k < 2048; k += 256){
    if(row[k] >= thrv){
      int p = atomicAdd(wcnt, 1);
      if(p < WCAP) wl[p] = make_int2(i, j0 + k);
    }
  }
}

// ---------------- verify: exact fp32 dot for each candidate, atomicMax into skeyx ----------------
__global__ __launch_bounds__(256) void verify(const int2* __restrict__ wl,
                                              const int* __restrict__ wcnt,
                                              const float* __restrict__ V,
                                              const float* __restrict__ T,
                                              const float* __restrict__ invv,
                                              const float* __restrict__ invt,
                                              const int* __restrict__ mv,
                                              unsigned* __restrict__ skeyx){
  int n = min(*wcnt, WCAP);
  __shared__ float red[4];
  for(int w = blockIdx.x; w < n; w += gridDim.x){
    int2 e = wl[w];
    const float4* vp = (const float4*)(V + (size_t)e.x*DK);
    const float4* tp = (const float4*)(T + (size_t)e.y*DK);
    float s = 0.f;
    for(int c = threadIdx.x; c < DK/4; c += 256){
      float4 a = vp[c], b = tp[c];
      s += a.x*b.x + a.y*b.y + a.z*b.z + a.w*b.w;
    }
    for(int d = 32; d > 0; d >>= 1) s += __shfl_down(s, d);
    if((threadIdx.x & 63) == 0) red[threadIdx.x >> 6] = s;
    __syncthreads();
    if(threadIdx.x == 0){
      float tot = red[0] + red[1] + red[2] + red[3];
      float val = (mv[e.y] != 0) ? tot * invv[e.x] * invt[e.y] : 0.0f;
      atomicMax(skeyx + e.x, fkey(val));
    }
    __syncthreads();
  }
}

// ---------------- selection: softmax -> sort -> cumsum -> neighbors -> unique ----------------
__global__ __launch_bounds__(512) void select_kernel(const unsigned* __restrict__ skey,
                                                     int* __restrict__ uniq,
                                                     int* __restrict__ ucnt){
  __shared__ float s[NV];
  __shared__ float pv[1024];
  __shared__ int   pi[1024];
  __shared__ int   flags[NV];
  __shared__ float red8[8];
  __shared__ float mval, sval;
  __shared__ int   sthr;
  __shared__ int   wsum[9], woff[9];
  __shared__ int   totcnt;
  int tid = threadIdx.x;
  int lane = tid & 63, w = tid >> 6;

  for(int i = tid; i < NV; i += 512) s[i] = fkey_inv(skey[i]) / 0.05f;
  __syncthreads();
  float pm = -3.402823e38f;
  for(int i = tid; i < NV; i += 512) pm = fmaxf(pm, s[i]);
  for(int d = 32; d > 0; d >>= 1) pm = fmaxf(pm, __shfl_xor(pm, d));
  if(lane == 0) red8[w] = pm;
  __syncthreads();
  if(tid == 0){
    float m = red8[0];
    for(int q = 1; q < 8; q++) m = fmaxf(m, red8[q]);
    mval = m;
  }
  __syncthreads();
  float m = mval;
  float ps = 0.f;
  for(int i = tid; i < NV; i += 512){ float e = expf(s[i] - m); s[i] = e; ps += e; }
  for(int d = 32; d > 0; d >>= 1) ps += __shfl_xor(ps, d);
  if(lane == 0) red8[w] = ps;
  __syncthreads();
  if(tid == 0){
    float t = 0.f;
    for(int q = 0; q < 8; q++) t += red8[q];
    sval = t;
  }
  __syncthreads();
  float S = sval;
  for(int i = tid; i < 1024; i += 512){
    if(i < NV){ pv[i] = s[i] / S; pi[i] = i; }
    else      { pv[i] = -3.402823e38f; pi[i] = i; }
  }
  __syncthreads();
  for(int k = 2; k <= 1024; k <<= 1){
    for(int j = k >> 1; j > 0; j >>= 1){
      for(int i = tid; i < 1024; i += 512){
        int ixj = i ^ j;
        if(ixj > i){
          bool dir = ((i & k) == 0);
          float v1 = pv[i], v2 = pv[ixj];
          int   a1 = pi[i], a2 = pi[ixj];
          bool b2first = (v2 > v1) || (v2 == v1 && a2 < a1);
          if(b2first == dir){
            pv[i] = v2; pv[ixj] = v1; pi[i] = a2; pi[ixj] = a1;
          }
        }
      }
      __syncthreads();
    }
  }
  if(tid == 0){
    float cum = 0.f; int thr = 0;
    #pragma unroll 8
    for(int i = 0; i < NV; i++){
      cum += pv[i];
      thr += (cum <= 0.5f) ? 1 : 0;
    }
    sthr = thr;
  }
  for(int i = tid; i < NV; i += 512) flags[i] = 0;
  __syncthreads();
  int thr = sthr;
  for(int i = tid; i < thr; i += 512){
    int sel = pi[i];
    int r = sel / GRID_N, c = sel % GRID_N;
    #pragma unroll
    for(int dr = -1; dr <= 1; dr++){
      #pragma unroll
      for(int dc = -1; dc <= 1; dc++){
        if(dr == 0 && dc == 0) continue;
        int rr = min(max(r + dr, 0), GRID_N - 1);
        int cc = min(max(c + dc, 0), GRID_N - 1);
        flags[rr*GRID_N + cc] = 1;
      }
    }
  }
  __syncthreads();
  int f0 = flags[tid];
  unsigned long long m0 = __ballot(f0 != 0);
  int r0 = __popcll(m0 & ((1ull << lane) - 1));
  if(lane == 0) wsum[w] = __popcll(m0);
  int f1 = 0, r1 = 0;
  if(tid < 64){
    f1 = flags[512 + tid];
    unsigned long long m1 = __ballot(f1 != 0);
    r1 = __popcll(m1 & ((1ull << lane) - 1));
    if(lane == 0) wsum[8] = __popcll(m1);
  }
  __syncthreads();
  if(tid == 0){
    int acc = 0;
    for(int c = 0; c < 9; c++){ woff[c] = acc; acc += wsum[c]; }
    totcnt = acc;
    *ucnt = acc;
  }
  __syncthreads();
  if(f0) uniq[woff[w] + r0] = tid;
  if(tid < 64 && f1) uniq[woff[8] + r1] = 512 + tid;
  int cnt = totcnt;
  for(int i = tid; i < NV; i += 512) if(i >= cnt) uniq[i] = 0;
}

// ---------------- per-row top-16 + softmax-weighted feature sum ----------------
__global__ __launch_bounds__(256) void topk_out_kernel(const float* __restrict__ mat,
                                                       const int* __restrict__ uniq,
                                                       int use_uniq,
                                                       const float* __restrict__ V,
                                                       float* __restrict__ out,
                                                       int U){
  int u = blockIdx.x;
  int rrow = use_uniq ? uniq[u] : u;
  __shared__ float s[NV];
  __shared__ float wv[TOPK];
  __shared__ int   wi[TOPK];
  __shared__ float rv[4];
  __shared__ int   ri[4];
  __shared__ float w[TOPK];
  int tid = threadIdx.x;
  const float* row = mat + (size_t)rrow*NV;
  for(int i = tid; i < NV; i += 256) s[i] = row[i];
  __syncthreads();
  for(int k = 0; k < TOPK; k++){
    float bv = -3.402823e38f; int bi = 1 << 30;
    for(int i = tid; i < NV; i += 256){
      float v = s[i];
      if(v > bv || (v == bv && i < bi)){ bv = v; bi = i; }
    }
    for(int o = 32; o > 0; o >>= 1){
      float ov = __shfl_down(bv, o);
      int   oi = __shfl_down(bi, o);
      if(ov > bv || (ov == bv && oi < bi)){ bv = ov; bi = oi; }
    }
    int lane = tid & 63, wd = tid >> 6;
    if(lane == 0){ rv[wd] = bv; ri[wd] = bi; }
    __syncthreads();
    if(tid == 0){
      float fv = rv[0]; int fi = ri[0];
      for(int q = 1; q < 4; q++){
        if(rv[q] > fv || (rv[q] == fv && ri[q] < fi)){ fv = rv[q]; fi = ri[q]; }
      }
      wv[k] = fv; wi[k] = fi;
      s[fi] = -3.402823e38f;
    }
    __syncthreads();
  }
  if(tid == 0){
    float mx = wv[0];
    float sum = 0.f;
    for(int k = 0; k < TOPK; k++){ float e = expf(wv[k] - mx); w[k] = e; sum += e; }
    for(int k = 0; k < TOPK; k++) w[k] /= sum;
  }
  __syncthreads();
  for(int c = tid; c < DK/4; c += 256){
    float4 acc = {0.f, 0.f, 0.f, 0.f};
    #pragma unroll
    for(int k = 0; k < TOPK; k++){
      float4 v = *((const float4*)(V + (size_t)wi[k]*DK) + c);
      float wk = w[k];
      acc.x = fmaf(wk, v.x, acc.x);
      acc.y = fmaf(wk, v.y, acc.y);
      acc.z = fmaf(wk, v.z, acc.z);
      acc.w = fmaf(wk, v.w, acc.w);
    }
    *((float4*)(out + (size_t)u*DK) + c) = acc;
  }
}

// ================= FALLBACK PATH (small workspace) =================
__global__ __launch_bounds__(256) void rownorm_kernel(const float* __restrict__ x,
                                                      float* __restrict__ invn){
  int r = blockIdx.x;
  const float4* p = (const float4*)(x + (size_t)r * DK);
  float s = 0.f;
  for(int c = threadIdx.x; c < DK/4; c += 256){
    float4 v = p[c];
    s += v.x*v.x + v.y*v.y + v.z*v.z + v.w*v.w;
  }
  for(int o = 32; o > 0; o >>= 1) s += __shfl_down(s, o);
  __shared__ float r4[4];
  int lane = threadIdx.x & 63, w = threadIdx.x >> 6;
  if(lane == 0) r4[w] = s;
  __syncthreads();
  if(threadIdx.x == 0){
    float t = r4[0] + r4[1] + r4[2] + r4[3];
    invn[r] = 1.0f / fmaxf(sqrtf(t), 1e-8f);
  }
}

__global__ __launch_bounds__(256) void mask_expand(const unsigned char* __restrict__ mraw,
                                                   int* __restrict__ mv){
  unsigned b0 = mraw[0], b1 = mraw[1], b2 = mraw[2], b3 = mraw[3];
  int j = blockIdx.x * 256 + threadIdx.x;
  if(j >= NT) return;
  bool isf32 = (b0 == 0 && b1 == 0 && b2 == 0x80 && b3 == 0x3F);
  if(isf32){
    mv[j] = (((const float*)mraw)[j] != 0.0f) ? 1 : 0;
  } else if((b1 | b2 | b3) != 0){
    mv[j] = mraw[j] ? 1 : 0;
  } else {
    mv[j] = (((const int*)mraw)[j] != 0) ? 1 : 0;
  }
}

__device__ __forceinline__ void cvt8v(float4 u, float4 v, bf16x8& h, bf16x8& l){
  float buf[8] = {u.x, u.y, u.z, u.w, v.x, v.y, v.z, v.w};
  #pragma unroll
  for(int i = 0; i < 8; i++){
    float f = buf[i];
    __bf16 hi = (__bf16)f;
    h[i] = hi;
    l[i] = (__bf16)(f - (float)hi);
  }
}

__global__ __launch_bounds__(256) void score_mfma(const float* __restrict__ V,
                                                  const float* __restrict__ T,
                                                  const float* __restrict__ invv,
                                                  const float* __restrict__ invt,
                                                  const int* __restrict__ mv,
                                                  unsigned* __restrict__ skey){
  __shared__ __align__(16) char lds[49152];
  __bf16* Ah = (__bf16*)lds;
  __bf16* Al = (__bf16*)(lds + 8192);
  __bf16* Bh = (__bf16*)(lds + 16384);
  __bf16* Bl = (__bf16*)(lds + 32768);
  int tid = threadIdx.x;
  int l = tid & 63, wid = tid >> 6;
  int wr = wid >> 1, n0 = (wid & 1) * 64;
  int vbase = blockIdx.y * 64, tbase = blockIdx.x * 128;
  int arow = tid >> 2;
  int brow = tid >> 1;
  const float* aptr = V + (size_t)(vbase + arow) * DK + (tid & 3) * 16;
  const float* bptr = T + (size_t)(tbase + brow) * DK + (tid & 1) * 32;
  f32x4 acc[2][4];
  #pragma unroll
  for(int i = 0; i < 2; i++)
    #pragma unroll
    for(int j = 0; j < 4; j++) acc[i][j] = (f32x4){0.f, 0.f, 0.f, 0.f};
  float4 fa[4], fb[8];
  #pragma unroll
  for(int c = 0; c < 4; c++) fa[c] = *(const float4*)(aptr + 4*c);
  #pragma unroll
  for(int c = 0; c < 8; c++) fb[c] = *(const float4*)(bptr + 4*c);
  int aswz = arow & 7, bswz = brow & 7;
  for(int k0 = 0; k0 < DK; k0 += 64){
    #pragma unroll
    for(int hhalf = 0; hhalf < 2; hhalf++){
      bf16x8 hv, lv; cvt8v(fa[2*hhalf], fa[2*hhalf+1], hv, lv);
      int slot = (tid & 3)*2 + hhalf;
      int off = arow*64 + ((slot ^ aswz) << 3);
      *(bf16x8*)(Ah + off) = hv; *(bf16x8*)(Al + off) = lv;
    }
    #pragma unroll
    for(int c = 0; c < 4; c++){
      bf16x8 hv, lv; cvt8v(fb[2*c], fb[2*c+1], hv, lv);
      int slot = (tid & 1)*4 + c;
      int off = brow*64 + ((slot ^ bswz) << 3);
      *(bf16x8*)(Bh + off) = hv; *(bf16x8*)(Bl + off) = lv;
    }
    __syncthreads();
    if(k0 + 64 < DK){
      #pragma unroll
      for(int c = 0; c < 4; c++) fa[c] = *(const float4*)(aptr + k0 + 64 + 4*c);
      #pragma unroll
      for(int c = 0; c < 8; c++) fb[c] = *(const float4*)(bptr + k0 + 64 + 4*c);
    }
    #pragma unroll
    for(int kc = 0; kc < 2; kc++){
      bf16x8 ah[2], al[2], bh[4], bl[4];
      int sa = kc*4 + (l >> 4);
      #pragma unroll
      for(int fm = 0; fm < 2; fm++){
        int ra = wr*32 + fm*16 + (l & 15);
        int oa = ra*64 + ((sa ^ (ra & 7)) << 3);
        ah[fm] = *(bf16x8*)(Ah + oa);
        al[fm] = *(bf16x8*)(Al + oa);
      }
      #pragma unroll
      for(int fn = 0; fn < 4; fn++){
        int rb = n0 + fn*16 + (l & 15);
        int ob = rb*64 + ((sa ^ (rb & 7)) << 3);
        bh[fn] = *(bf16x8*)(Bh + ob);
        bl[fn] = *(bf16x8*)(Bl + ob);
      }
      #pragma unroll
      for(int fm = 0; fm < 2; fm++)
        #pragma unroll
        for(int fn = 0; fn < 4; fn++){
          acc[fm][fn] = __builtin_amdgcn_mfma_f32_16x16x32_bf16(ah[fm], bh[fn], acc[fm][fn], 0, 0, 0);
          acc[fm][fn] = __builtin_amdgcn_mfma_f32_16x16x32_bf16(al[fm], bh[fn], acc[fm][fn], 0, 0, 0);
          acc[fm][fn] = __builtin_amdgcn_mfma_f32_16x16x32_bf16(ah[fm], bl[fn], acc[fm][fn], 0, 0, 0);
        }
    }
    __syncthreads();
  }
  float* red = (float*)lds;
  float itc[4];
  #pragma unroll
  for(int fn = 0; fn < 4; fn++){
    int col = tbase + n0 + fn*16 + (l & 15);
    itc[fn] = (mv[col] != 0) ? invt[col] : 0.0f;
  }
  #pragma unroll
  for(int fm = 0; fm < 2; fm++){
    float rm[4];
    #pragma unroll
    for(int e = 0; e < 4; e++){
      int grow = vbase + wr*32 + fm*16 + ((l >> 4) << 2) + e;
      float ivv = invv[grow];
      float mx =     acc[fm][0][e] * itc[0];
      mx = fmaxf(mx, acc[fm][1][e] * itc[1]);
      mx = fmaxf(mx, acc[fm][2][e] * itc[2]);
      mx = fmaxf(mx, acc[fm][3][e] * itc[3]);
      rm[e] = mx * ivv;
    }
    #pragma unroll
    for(int d = 1; d < 16; d <<= 1){
      #pragma unroll
      for(int e = 0; e < 4; e++) rm[e] = fmaxf(rm[e], __shfl_xor(rm[e], d, 16));
    }
    if((l & 15) == 0){
      #pragma unroll
      for(int e = 0; e < 4; e++){
        int rl = wr*32 + fm*16 + ((l >> 4) << 2) + e;
        red[(wid & 1)*64 + rl] = rm[e];
      }
    }
  }
  __syncthreads();
  if(tid < 64){
    float m = fmaxf(red[tid], red[64 + tid]);
    atomicMax(skey + vbase + tid, fkey(m));
  }
}

__global__ __launch_bounds__(256) void scos_gemm(const float* __restrict__ V,
                                                 const int* __restrict__ uniq,
                                                 const float* __restrict__ invv,
                                                 float* __restrict__ scos,
                                                 int U){
  __shared__ __align__(16) float As[32*LDT];
  __shared__ __align__(16) float Bs[32*LDT];
  int tid = threadIdx.x;
  int tx = tid & 15, ty = tid >> 4;
  int ubase = blockIdx.y * 64, ibase = blockIdx.x * 64;
  int r0 = tid >> 3, r1 = r0 + 32;
  int kc = (tid & 7) << 2;
  int g0 = ubase + r0, g1 = ubase + r1;
  int arow0 = (g0 < U) ? uniq[g0] : 0;
  int arow1 = (g1 < U) ? uniq[g1] : 0;
  float acc[4][4] = {};
  for(int k0 = 0; k0 < DK; k0 += 32){
    __syncthreads();
    float4 a0 = *(const float4*)(V + (size_t)arow0*DK + k0 + kc);
    float4 a1 = *(const float4*)(V + (size_t)arow1*DK + k0 + kc);
    float4 b0 = *(const float4*)(V + (size_t)(ibase + r0)*DK + k0 + kc);
    float4 b1 = *(const float4*)(V + (size_t)(ibase + r1)*DK + k0 + kc);
    As[(kc+0)*LDT + r0] = a0.x; As[(kc+1)*LDT + r0] = a0.y; As[(kc+2)*LDT + r0] = a0.z; As[(kc+3)*LDT + r0] = a0.w;
    As[(kc+0)*LDT + r1] = a1.x; As[(kc+1)*LDT + r1] = a1.y; As[(kc+2)*LDT + r1] = a1.z; As[(kc+3)*LDT + r1] = a1.w;
    Bs[(kc+0)*LDT + r0] = b0.x; Bs[(kc+1)*LDT + r0] = b0.y; Bs[(kc+2)*LDT + r0] = b0.z; Bs[(kc+3)*LDT + r0] = b0.w;
    Bs[(kc+0)*LDT + r1] = b1.x; Bs[(kc+1)*LDT + r1] = b1.y; Bs[(kc+2)*LDT + r1] = b1.z; Bs[(kc+3)*LDT + r1] = b1.w;
    __syncthreads();
    #pragma unroll
    for(int k = 0; k < 32; k++){
      float4 a4 = *(const float4*)(As + k*LDT + ty*4);
      float4 b4 = *(const float4*)(Bs + k*LDT + tx*4);
      acc[0][0] += a4.x*b4.x; acc[0][1] += a4.x*b4.y; acc[0][2] += a4.x*b4.z; acc[0][3] += a4.x*b4.w;
      acc[1][0] += a4.y*b4.x; acc[1][1] += a4.y*b4.y; acc[1][2] += a4.y*b4.z; acc[1][3] += a4.y*b4.w;
      acc[2][0] += a4.z*b4.x; acc[2][1] += a4.z*b4.y; acc[2][2] += a4.z*b4.z; acc[2][3] += a4.z*b4.w;
      acc[3][0] += a4.w*b4.x; acc[3][1] += a4.w*b4.y; acc[3][2] += a4.w*b4.z; acc[3][3] += a4.w*b4.w;
    }
  }
  #pragma unroll
  for(int a = 0; a < 4; a++){
    int gu = ubase + ty*4 + a;
    if(gu < U){
      float su = invv[uniq[gu]];
      #pragma unroll
      for(int b = 0; b < 4; b++){
        int i = ibase + tx*4 + b;
        scos[(size_t)gu*NV + i] = acc[a][b] * su * invv[i];
      }
    }
  }
}

// ================= launch =================
extern "C" void kernel_launch(void* const* d_in, const int* in_sizes, int n_in,
                              void* d_out, int out_size, void* d_ws, size_t ws_size,
                              hipStream_t stream){
  const float* V = (const float*)d_in[0];
  const float* T = (const float*)d_in[1];
  const unsigned char* mraw = (const unsigned char*)d_in[2];
  float* out = (float*)d_out;
  int U = out_size / DK;

  // workspace layout (byte offsets, 256-aligned)
  char* W = (char*)d_ws;
  float*    invv  = (float*)W;                  // 576 f
  float*    invt  = (float*)(W + 2560);         // 8192 f
  unsigned* skeyx = (unsigned*)(W + 35584);     // 576 u (exact verified max)
  int*      uniq  = (int*)(W + 38144);          // 576 i
  int*      ucnt  = (int*)(W + 40448);
  unsigned* skey  = (unsigned*)(W + 40704);     // 576 u (approx max / fallback)
  int*      mv    = (int*)(W + 43264);          // 8192 i
  float*    G     = (float*)(W + 76032);        // 576*576 f (also fallback scos)
  __bf16*   Vh    = (__bf16*)(W + 1403136);     // 576*4096 bf16
  __bf16*   Vl    = (__bf16*)(W + 6121728);     // 576*4096 bf16
  float*    cosm  = (float*)(W + 10840320);     // 576*8192 f
  __bf16*   Th    = (__bf16*)(W + 29714688);    // 8192*4096 bf16
  // worklist overlaps Th's region: Th is dead after score_gram, collect runs after.
  int*      wcnt  = (int*)(W + 29714688);
  int2*     wl    = (int2*)(W + 29714944);
  const size_t MAIN_NEED = 96823552;

  if(ws_size >= MAIN_NEED){
    prep_all<<<NT + NV + 32, 256, 0, stream>>>(V, T, mraw, Vh, Vl, Th, invv, invt, mv,
                                               skey, skeyx, wcnt);
    score_gram<<<576 + 81, 256, 0, stream>>>(Vh, Vl, Th, invv, invt, mv, cosm, skey, G);
    collect<<<dim3(NV, 4), 256, 0, stream>>>(cosm, skey, wl, wcnt);
    verify<<<1024, 256, 0, stream>>>(wl, wcnt, V, T, invv, invt, mv, skeyx);
    select_kernel<<<1, 512, 0, stream>>>(skeyx, uniq, ucnt);
    if(U > 0){
      topk_out_kernel<<<U, 256, 0, stream>>>(G, uniq, 1, V, out, U);
    }
  } else {
    hipMemsetAsync(skey, 0, NV*sizeof(unsigned), stream);
    mask_expand<<<(NT + 255)/256, 256, 0, stream>>>(mraw, mv);
    rownorm_kernel<<<NV, 256, 0, stream>>>(V, invv);
    rownorm_kernel<<<NT, 256, 0, stream>>>(T, invt);
    score_mfma<<<dim3(NT/128, NV/64), 256, 0, stream>>>(V, T, invv, invt, mv, skey);
    select_kernel<<<1, 512, 0, stream>>>(skey, uniq, ucnt);
    if(U > 0){
      scos_gemm<<<dim3(NV/64, (U + 63)/64), 256, 0, stream>>>(V, uniq, invv, G, U);
      topk_out_kernel<<<U, 256, 0, stream>>>(G, uniq, 0, V, out, U);
    }
  }
}

// Round 13
// 213.808 us; speedup vs baseline: 1.0237x; 1.0237x over previous
//
#include <hip/hip_runtime.h>
#include <hip/hip_bf16.h>
#include <math.h>

#define GRID_N 24
#define NV 576
#define NT 8192
#define DK 4096
#define TOPK 16
#define LDT 68       // padded leading dim for fp32 [k][m] LDS tiles (fallback scos kernel)
#define DELTA 0.005f // Gaussian inputs: hi*hi dot error std ~2.4e-5, max ~1.3e-4 -> 38x margin
#define WCAP 32768

typedef __bf16 bf16x8 __attribute__((ext_vector_type(8)));
typedef __bf16 bf16x4 __attribute__((ext_vector_type(4)));
typedef float  f32x4  __attribute__((ext_vector_type(4)));

__device__ __forceinline__ unsigned fkey(float f){
  unsigned u = __float_as_uint(f);
  return (u & 0x80000000u) ? ~u : (u | 0x80000000u);
}
__device__ __forceinline__ float fkey_inv(unsigned u){
  unsigned b = (u & 0x80000000u) ? (u & 0x7fffffffu) : ~u;
  return __uint_as_float(b);
}

__device__ __forceinline__ void gload_lds16(const void* g, void* l){
  __builtin_amdgcn_global_load_lds((const __attribute__((address_space(1))) unsigned*)g,
                                   (__attribute__((address_space(3))) unsigned*)l, 16, 0, 0);
}

// ---------------- prep_all: T-norm+bf16 | V-norm+hi/lo split | mask expand + zero-init ----------------
__global__ __launch_bounds__(256) void prep_all(const float* __restrict__ V,
                                                const float* __restrict__ T,
                                                const unsigned char* __restrict__ mraw,
                                                __bf16* __restrict__ Vh,
                                                __bf16* __restrict__ Vl,
                                                __bf16* __restrict__ Th,
                                                float* __restrict__ invv,
                                                float* __restrict__ invt,
                                                int* __restrict__ mv,
                                                unsigned* __restrict__ skey,
                                                unsigned* __restrict__ skeyx,
                                                int* __restrict__ wcnt){
  int bid = blockIdx.x;
  int tid = threadIdx.x;
  if(bid < NT){
    int r = bid;
    const float4* p = (const float4*)(T + (size_t)r * DK);
    __bf16* o = Th + (size_t)r * DK;
    float s = 0.f;
    for(int c = tid; c < DK/4; c += 256){
      float4 v = p[c];
      s += v.x*v.x + v.y*v.y + v.z*v.z + v.w*v.w;
      bf16x4 h = { (__bf16)v.x, (__bf16)v.y, (__bf16)v.z, (__bf16)v.w };
      *(bf16x4*)(o + c*4) = h;
    }
    for(int d = 32; d > 0; d >>= 1) s += __shfl_down(s, d);
    __shared__ float r4[4];
    if((tid & 63) == 0) r4[tid >> 6] = s;
    __syncthreads();
    if(tid == 0){
      float t = r4[0] + r4[1] + r4[2] + r4[3];
      invt[r] = 1.0f / fmaxf(sqrtf(t), 1e-8f);
    }
  } else if(bid < NT + NV){
    int r = bid - NT;
    const float4* p = (const float4*)(V + (size_t)r * DK);
    __bf16* oh = Vh + (size_t)r * DK;
    __bf16* ol = Vl + (size_t)r * DK;
    float s = 0.f;
    for(int c = tid; c < DK/4; c += 256){
      float4 v = p[c];
      s += v.x*v.x + v.y*v.y + v.z*v.z + v.w*v.w;
      float f[4] = {v.x, v.y, v.z, v.w};
      bf16x4 h, l;
      #pragma unroll
      for(int q = 0; q < 4; q++){
        __bf16 hv = (__bf16)f[q];
        h[q] = hv;
        l[q] = (__bf16)(f[q] - (float)hv);
      }
      *(bf16x4*)(oh + c*4) = h;
      *(bf16x4*)(ol + c*4) = l;
    }
    for(int d = 32; d > 0; d >>= 1) s += __shfl_down(s, d);
    __shared__ float r4v[4];
    if((tid & 63) == 0) r4v[tid >> 6] = s;
    __syncthreads();
    if(tid == 0){
      float t = r4v[0] + r4v[1] + r4v[2] + r4v[3];
      invv[r] = 1.0f / fmaxf(sqrtf(t), 1e-8f);
    }
  } else {
    int mb = bid - NT - NV;
    int j = mb*256 + tid;
    if(j < NT){
      unsigned b0 = mraw[0], b1 = mraw[1], b2 = mraw[2], b3 = mraw[3];
      bool isf32 = (b0 == 0 && b1 == 0 && b2 == 0x80 && b3 == 0x3F);
      if(isf32)                 mv[j] = (((const float*)mraw)[j] != 0.0f) ? 1 : 0;
      else if((b1|b2|b3) != 0)  mv[j] = mraw[j] ? 1 : 0;
      else                      mv[j] = (((const int*)mraw)[j] != 0) ? 1 : 0;
    }
    if(mb == 0){
      for(int i = tid; i < NV; i += 256){ skey[i] = 0u; skeyx[i] = 0u; }
      if(tid == 0) *wcnt = 0;
    }
  }
}

// ---------------- fused score1 + gram ----------------
// blocks [0,576): cosm~ = Vh @ Th^T * iv*it (mask->0) + row-max atomic, XCD-swizzled.
//   SINGLE-buffer LDS (24 KB; block LDS 32 KB -> 5 blocks/CU, ~20 waves) — trade
//   intra-block pipelining for TLP: co-resident blocks at different phases hide
//   the stage/drain stalls (m114). setprio(1) around the MFMA cluster (T5).
// blocks [576,657): G = normalize(V)@normalize(V)^T 3-pass split-bf16 (single buffer).
__global__ __launch_bounds__(256) void score_gram(const __bf16* __restrict__ Vh,
                                                  const __bf16* __restrict__ Vl,
                                                  const __bf16* __restrict__ Th,
                                                  const float* __restrict__ invv,
                                                  const float* __restrict__ invt,
                                                  const int* __restrict__ mv,
                                                  float* __restrict__ cosm,
                                                  unsigned* __restrict__ skey,
                                                  float* __restrict__ G){
  __shared__ __align__(16) char lds[32768];
  int tid = threadIdx.x;
  int l = tid & 63, wid = tid >> 6;

  if(blockIdx.x < 576){
    // ================= score body (single-buffer, high occupancy) =================
    __bf16* sA0 = (__bf16*)lds;            // 64 x 64  =  8 KB
    __bf16* sB0 = (__bf16*)(lds + 8192);   // 128 x 64 = 16 KB
    int m0 = (wid >> 1) * 32, n0 = (wid & 1) * 64;
    int bid = blockIdx.x;
    int orig = (bid & 7) * 72 + (bid >> 3);   // XCD x owns orig [x*72, x*72+72)
    int jt = orig / 9, it = orig % 9;          // j-major within XCD chunk
    int vbase = it * 64, tbase = jt * 128;

    // staging: 24 gload_lds16 per K-step, 6 per wave
    const __bf16* gsrc[6];
    __bf16* l0[6];
    #pragma unroll
    for(int q = 0; q < 6; q++){
      int inst = wid*6 + q;
      int which = inst >> 3;
      int i = inst & 7;
      int r8 = i*8 + (l >> 3);
      int swz = ((l & 7) ^ (r8 & 7)) << 3;   // pre-swizzled global source, linear LDS dest
      if(which == 0){
        gsrc[q] = Vh + (size_t)(vbase + r8)*DK + swz;
        l0[q] = sA0 + i*512;
      } else if(which == 1){
        gsrc[q] = Th + (size_t)(tbase + r8)*DK + swz;
        l0[q] = sB0 + i*512;
      } else {
        gsrc[q] = Th + (size_t)(tbase + 64 + r8)*DK + swz;
        l0[q] = sB0 + (8+i)*512;
      }
    }

    // hoisted per-kc LDS fragment offsets
    int aoffk[2][2], boffk[2][4];
    #pragma unroll
    for(int kc = 0; kc < 2; kc++){
      int sa = kc*4 + (l >> 4);
      #pragma unroll
      for(int fm = 0; fm < 2; fm++){
        int ra = m0 + fm*16 + (l & 15);
        aoffk[kc][fm] = ra*64 + ((sa ^ (ra & 7)) << 3);
      }
      #pragma unroll
      for(int fn = 0; fn < 4; fn++){
        int rb = n0 + fn*16 + (l & 15);
        boffk[kc][fn] = rb*64 + ((sa ^ (rb & 7)) << 3);
      }
    }

    f32x4 acc[2][4];
    #pragma unroll
    for(int i = 0; i < 2; i++)
      #pragma unroll
      for(int j = 0; j < 4; j++) acc[i][j] = (f32x4){0.f,0.f,0.f,0.f};

    for(int t = 0; t < DK/64; t++){
      __syncthreads();   // WAR: previous step's reads done before re-staging
      #pragma unroll
      for(int q = 0; q < 6; q++) gload_lds16(gsrc[q] + t*64, l0[q]);
      __syncthreads();   // compiler drains vmcnt before barrier: tile resident
      __builtin_amdgcn_s_setprio(1);
      #pragma unroll
      for(int kc = 0; kc < 2; kc++){
        bf16x8 ah[2], bh[4];
        #pragma unroll
        for(int fm = 0; fm < 2; fm++)
          ah[fm] = *(bf16x8*)(sA0 + aoffk[kc][fm]);
        #pragma unroll
        for(int fn = 0; fn < 4; fn++)
          bh[fn] = *(bf16x8*)(sB0 + boffk[kc][fn]);
        #pragma unroll
        for(int fm = 0; fm < 2; fm++)
          #pragma unroll
          for(int fn = 0; fn < 4; fn++)
            acc[fm][fn] = __builtin_amdgcn_mfma_f32_16x16x32_bf16(ah[fm], bh[fn], acc[fm][fn], 0, 0, 0);
      }
      __builtin_amdgcn_s_setprio(0);
    }
    __syncthreads();   // all waves done with sA/sB before aliasing as reduction buf

    // epilogue: scale + mask, write cos~ tile, fused per-row approx max -> atomicMax(fkey)
    float* red = (float*)lds;
    float itc[4];
    #pragma unroll
    for(int fn = 0; fn < 4; fn++){
      int col = tbase + n0 + fn*16 + (l & 15);
      itc[fn] = (mv[col] != 0) ? invt[col] : 0.0f;
    }
    #pragma unroll
    for(int fm = 0; fm < 2; fm++){
      float rm[4];
      #pragma unroll
      for(int e = 0; e < 4; e++){
        int grow = vbase + m0 + fm*16 + ((l >> 4) << 2) + e;
        float iv = invv[grow];
        float mx = -3.402823e38f;
        #pragma unroll
        for(int fn = 0; fn < 4; fn++){
          int col = tbase + n0 + fn*16 + (l & 15);
          float val = acc[fm][fn][e] * iv * itc[fn];
          cosm[(size_t)grow*NT + col] = val;
          mx = fmaxf(mx, val);
        }
        rm[e] = mx;
      }
      #pragma unroll
      for(int d = 1; d < 16; d <<= 1){
        #pragma unroll
        for(int e = 0; e < 4; e++) rm[e] = fmaxf(rm[e], __shfl_xor(rm[e], d, 16));
      }
      if((l & 15) == 0){
        #pragma unroll
        for(int e = 0; e < 4; e++){
          int rl = m0 + fm*16 + ((l >> 4) << 2) + e;
          red[(wid & 1)*64 + rl] = rm[e];
        }
      }
    }
    __syncthreads();
    if(tid < 64){
      float m = fmaxf(red[tid], red[64 + tid]);
      atomicMax(skey + vbase + tid, fkey(m));
    }
  } else {
    // ================= gram body (single-buffered) =================
    __bf16* sAh = (__bf16*)lds;
    __bf16* sAl = (__bf16*)(lds + 8192);
    __bf16* sBh = (__bf16*)(lds + 16384);
    __bf16* sBl = (__bf16*)(lds + 24576);
    int m0 = (wid >> 1) * 32, n0 = (wid & 1) * 32;
    int gb = blockIdx.x - 576;
    int ubase = (gb / 9) * 64, ibase = (gb % 9) * 64;

    const __bf16* gsrc[8];
    __bf16* ldst[8];
    #pragma unroll
    for(int q = 0; q < 8; q++){
      int inst = wid*8 + q;
      int which = inst >> 3;
      int i = inst & 7;
      int rl = i*8 + (l >> 3);
      const __bf16* base;
      __bf16* lb;
      if(which == 0){      base = Vh + (size_t)(ubase + rl)*DK; lb = sAh + i*512; }
      else if(which == 1){ base = Vl + (size_t)(ubase + rl)*DK; lb = sAl + i*512; }
      else if(which == 2){ base = Vh + (size_t)(ibase + rl)*DK; lb = sBh + i*512; }
      else {               base = Vl + (size_t)(ibase + rl)*DK; lb = sBl + i*512; }
      int chunk_g = (l & 7) ^ (rl & 7);
      gsrc[q] = base + chunk_g*8;
      ldst[q] = lb;
    }

    int aoffk[2][2], boffk[2][2];
    #pragma unroll
    for(int kc = 0; kc < 2; kc++){
      int sa = kc*4 + (l >> 4);
      #pragma unroll
      for(int f = 0; f < 2; f++){
        int ra = m0 + f*16 + (l & 15);
        aoffk[kc][f] = ra*64 + ((sa ^ (ra & 7)) << 3);
        int rb = n0 + f*16 + (l & 15);
        boffk[kc][f] = rb*64 + ((sa ^ (rb & 7)) << 3);
      }
    }

    f32x4 acc[2][2];
    #pragma unroll
    for(int i = 0; i < 2; i++)
      #pragma unroll
      for(int j = 0; j < 2; j++) acc[i][j] = (f32x4){0.f,0.f,0.f,0.f};

    for(int k0 = 0; k0 < DK; k0 += 64){
      __syncthreads();
      #pragma unroll
      for(int q = 0; q < 8; q++) gload_lds16(gsrc[q] + k0, ldst[q]);
      __syncthreads();
      #pragma unroll
      for(int kc = 0; kc < 2; kc++){
        bf16x8 ah[2], al[2], bh[2], bl[2];
        #pragma unroll
        for(int f = 0; f < 2; f++){
          ah[f] = *(bf16x8*)(sAh + aoffk[kc][f]);
          al[f] = *(bf16x8*)(sAl + aoffk[kc][f]);
          bh[f] = *(bf16x8*)(sBh + boffk[kc][f]);
          bl[f] = *(bf16x8*)(sBl + boffk[kc][f]);
        }
        #pragma unroll
        for(int fm = 0; fm < 2; fm++)
          #pragma unroll
          for(int fn = 0; fn < 2; fn++){
            acc[fm][fn] = __builtin_amdgcn_mfma_f32_16x16x32_bf16(ah[fm], bh[fn], acc[fm][fn], 0, 0, 0);
            acc[fm][fn] = __builtin_amdgcn_mfma_f32_16x16x32_bf16(al[fm], bh[fn], acc[fm][fn], 0, 0, 0);
            acc[fm][fn] = __builtin_amdgcn_mfma_f32_16x16x32_bf16(ah[fm], bl[fn], acc[fm][fn], 0, 0, 0);
          }
      }
    }

    #pragma unroll
    for(int fm = 0; fm < 2; fm++){
      #pragma unroll
      for(int e = 0; e < 4; e++){
        int grow = ubase + m0 + fm*16 + ((l >> 4) << 2) + e;
        float su = invv[grow];
        #pragma unroll
        for(int fn = 0; fn < 2; fn++){
          int gcol = ibase + n0 + fn*16 + (l & 15);
          G[(size_t)grow*NV + gcol] = acc[fm][fn][e] * su * invv[gcol];
        }
      }
    }
  }
}

// ---------------- collect: stream cosm, emit near-max candidates to worklist ----------------
__global__ __launch_bounds__(256) void collect(const float* __restrict__ cosm,
                                               const unsigned* __restrict__ skey,
                                               int2* __restrict__ wl,
                                               int* __restrict__ wcnt){
  int i = blockIdx.x;
  float thrv = fkey_inv(skey[i]) - DELTA;
  int j0 = blockIdx.y * 2048;
  const float* row = cosm + (size_t)i*NT + j0;
  for(int k = threadIdx.x; k < 2048; k += 256){
    if(row[k] >= thrv){
      int p = atomicAdd(wcnt, 1);
      if(p < WCAP) wl[p] = make_int2(i, j0 + k);
    }
  }
}

// ---------------- verify: exact fp32 dot for each candidate, atomicMax into skeyx ----------------
__global__ __launch_bounds__(256) void verify(const int2* __restrict__ wl,
                                              const int* __restrict__ wcnt,
                                              const float* __restrict__ V,
                                              const float* __restrict__ T,
                                              const float* __restrict__ invv,
                                              const float* __restrict__ invt,
                                              const int* __restrict__ mv,
                                              unsigned* __restrict__ skeyx){
  int n = min(*wcnt, WCAP);
  __shared__ float red[4];
  for(int w = blockIdx.x; w < n; w += gridDim.x){
    int2 e = wl[w];
    const float4* vp = (const float4*)(V + (size_t)e.x*DK);
    const float4* tp = (const float4*)(T + (size_t)e.y*DK);
    float s = 0.f;
    for(int c = threadIdx.x; c < DK/4; c += 256){
      float4 a = vp[c], b = tp[c];
      s += a.x*b.x + a.y*b.y + a.z*b.z + a.w*b.w;
    }
    for(int d = 32; d > 0; d >>= 1) s += __shfl_down(s, d);
    if((threadIdx.x & 63) == 0) red[threadIdx.x >> 6] = s;
    __syncthreads();
    if(threadIdx.x == 0){
      float tot = red[0] + red[1] + red[2] + red[3];
      float val = (mv[e.y] != 0) ? tot * invv[e.x] * invt[e.y] : 0.0f;
      atomicMax(skeyx + e.x, fkey(val));
    }
    __syncthreads();
  }
}

// ---------------- selection: softmax -> sort -> cumsum -> neighbors -> unique ----------------
__global__ __launch_bounds__(512) void select_kernel(const unsigned* __restrict__ skey,
                                                     int* __restrict__ uniq,
                                                     int* __restrict__ ucnt){
  __shared__ float s[NV];
  __shared__ float pv[1024];
  __shared__ int   pi[1024];
  __shared__ int   flags[NV];
  __shared__ float red8[8];
  __shared__ float mval, sval;
  __shared__ int   sthr;
  __shared__ int   wsum[9], woff[9];
  __shared__ int   totcnt;
  int tid = threadIdx.x;
  int lane = tid & 63, w = tid >> 6;

  for(int i = tid; i < NV; i += 512) s[i] = fkey_inv(skey[i]) / 0.05f;
  __syncthreads();
  float pm = -3.402823e38f;
  for(int i = tid; i < NV; i += 512) pm = fmaxf(pm, s[i]);
  for(int d = 32; d > 0; d >>= 1) pm = fmaxf(pm, __shfl_xor(pm, d));
  if(lane == 0) red8[w] = pm;
  __syncthreads();
  if(tid == 0){
    float m = red8[0];
    for(int q = 1; q < 8; q++) m = fmaxf(m, red8[q]);
    mval = m;
  }
  __syncthreads();
  float m = mval;
  float ps = 0.f;
  for(int i = tid; i < NV; i += 512){ float e = expf(s[i] - m); s[i] = e; ps += e; }
  for(int d = 32; d > 0; d >>= 1) ps += __shfl_xor(ps, d);
  if(lane == 0) red8[w] = ps;
  __syncthreads();
  if(tid == 0){
    float t = 0.f;
    for(int q = 0; q < 8; q++) t += red8[q];
    sval = t;
  }
  __syncthreads();
  float S = sval;
  for(int i = tid; i < 1024; i += 512){
    if(i < NV){ pv[i] = s[i] / S; pi[i] = i; }
    else      { pv[i] = -3.402823e38f; pi[i] = i; }
  }
  __syncthreads();
  for(int k = 2; k <= 1024; k <<= 1){
    for(int j = k >> 1; j > 0; j >>= 1){
      for(int i = tid; i < 1024; i += 512){
        int ixj = i ^ j;
        if(ixj > i){
          bool dir = ((i & k) == 0);
          float v1 = pv[i], v2 = pv[ixj];
          int   a1 = pi[i], a2 = pi[ixj];
          bool b2first = (v2 > v1) || (v2 == v1 && a2 < a1);
          if(b2first == dir){
            pv[i] = v2; pv[ixj] = v1; pi[i] = a2; pi[ixj] = a1;
          }
        }
      }
      __syncthreads();
    }
  }
  if(tid == 0){
    float cum = 0.f; int thr = 0;
    #pragma unroll 8
    for(int i = 0; i < NV; i++){
      cum += pv[i];
      thr += (cum <= 0.5f) ? 1 : 0;
    }
    sthr = thr;
  }
  for(int i = tid; i < NV; i += 512) flags[i] = 0;
  __syncthreads();
  int thr = sthr;
  for(int i = tid; i < thr; i += 512){
    int sel = pi[i];
    int r = sel / GRID_N, c = sel % GRID_N;
    #pragma unroll
    for(int dr = -1; dr <= 1; dr++){
      #pragma unroll
      for(int dc = -1; dc <= 1; dc++){
        if(dr == 0 && dc == 0) continue;
        int rr = min(max(r + dr, 0), GRID_N - 1);
        int cc = min(max(c + dc, 0), GRID_N - 1);
        flags[rr*GRID_N + cc] = 1;
      }
    }
  }
  __syncthreads();
  int f0 = flags[tid];
  unsigned long long m0 = __ballot(f0 != 0);
  int r0 = __popcll(m0 & ((1ull << lane) - 1));
  if(lane == 0) wsum[w] = __popcll(m0);
  int f1 = 0, r1 = 0;
  if(tid < 64){
    f1 = flags[512 + tid];
    unsigned long long m1 = __ballot(f1 != 0);
    r1 = __popcll(m1 & ((1ull << lane) - 1));
    if(lane == 0) wsum[8] = __popcll(m1);
  }
  __syncthreads();
  if(tid == 0){
    int acc = 0;
    for(int c = 0; c < 9; c++){ woff[c] = acc; acc += wsum[c]; }
    totcnt = acc;
    *ucnt = acc;
  }
  __syncthreads();
  if(f0) uniq[woff[w] + r0] = tid;
  if(tid < 64 && f1) uniq[woff[8] + r1] = 512 + tid;
  int cnt = totcnt;
  for(int i = tid; i < NV; i += 512) if(i >= cnt) uniq[i] = 0;
}

// ---------------- per-row top-16 + softmax-weighted feature sum ----------------
__global__ __launch_bounds__(256) void topk_out_kernel(const float* __restrict__ mat,
                                                       const int* __restrict__ uniq,
                                                       int use_uniq,
                                                       const float* __restrict__ V,
                                                       float* __restrict__ out,
                                                       int U){
  int u = blockIdx.x;
  int rrow = use_uniq ? uniq[u] : u;
  __shared__ float s[NV];
  __shared__ float wv[TOPK];
  __shared__ int   wi[TOPK];
  __shared__ float rv[4];
  __shared__ int   ri[4];
  __shared__ float w[TOPK];
  int tid = threadIdx.x;
  const float* row = mat + (size_t)rrow*NV;
  for(int i = tid; i < NV; i += 256) s[i] = row[i];
  __syncthreads();
  for(int k = 0; k < TOPK; k++){
    float bv = -3.402823e38f; int bi = 1 << 30;
    for(int i = tid; i < NV; i += 256){
      float v = s[i];
      if(v > bv || (v == bv && i < bi)){ bv = v; bi = i; }
    }
    for(int o = 32; o > 0; o >>= 1){
      float ov = __shfl_down(bv, o);
      int   oi = __shfl_down(bi, o);
      if(ov > bv || (ov == bv && oi < bi)){ bv = ov; bi = oi; }
    }
    int lane = tid & 63, wd = tid >> 6;
    if(lane == 0){ rv[wd] = bv; ri[wd] = bi; }
    __syncthreads();
    if(tid == 0){
      float fv = rv[0]; int fi = ri[0];
      for(int q = 1; q < 4; q++){
        if(rv[q] > fv || (rv[q] == fv && ri[q] < fi)){ fv = rv[q]; fi = ri[q]; }
      }
      wv[k] = fv; wi[k] = fi;
      s[fi] = -3.402823e38f;
    }
    __syncthreads();
  }
  if(tid == 0){
    float mx = wv[0];
    float sum = 0.f;
    for(int k = 0; k < TOPK; k++){ float e = expf(wv[k] - mx); w[k] = e; sum += e; }
    for(int k = 0; k < TOPK; k++) w[k] /= sum;
  }
  __syncthreads();
  for(int c = tid; c < DK/4; c += 256){
    float4 acc = {0.f, 0.f, 0.f, 0.f};
    #pragma unroll
    for(int k = 0; k < TOPK; k++){
      float4 v = *((const float4*)(V + (size_t)wi[k]*DK) + c);
      float wk = w[k];
      acc.x = fmaf(wk, v.x, acc.x);
      acc.y = fmaf(wk, v.y, acc.y);
      acc.z = fmaf(wk, v.z, acc.z);
      acc.w = fmaf(wk, v.w, acc.w);
    }
    *((float4*)(out + (size_t)u*DK) + c) = acc;
  }
}

// ================= FALLBACK PATH (small workspace) =================
__global__ __launch_bounds__(256) void rownorm_kernel(const float* __restrict__ x,
                                                      float* __restrict__ invn){
  int r = blockIdx.x;
  const float4* p = (const float4*)(x + (size_t)r * DK);
  float s = 0.f;
  for(int c = threadIdx.x; c < DK/4; c += 256){
    float4 v = p[c];
    s += v.x*v.x + v.y*v.y + v.z*v.z + v.w*v.w;
  }
  for(int o = 32; o > 0; o >>= 1) s += __shfl_down(s, o);
  __shared__ float r4[4];
  int lane = threadIdx.x & 63, w = threadIdx.x >> 6;
  if(lane == 0) r4[w] = s;
  __syncthreads();
  if(threadIdx.x == 0){
    float t = r4[0] + r4[1] + r4[2] + r4[3];
    invn[r] = 1.0f / fmaxf(sqrtf(t), 1e-8f);
  }
}

__global__ __launch_bounds__(256) void mask_expand(const unsigned char* __restrict__ mraw,
                                                   int* __restrict__ mv){
  unsigned b0 = mraw[0], b1 = mraw[1], b2 = mraw[2], b3 = mraw[3];
  int j = blockIdx.x * 256 + threadIdx.x;
  if(j >= NT) return;
  bool isf32 = (b0 == 0 && b1 == 0 && b2 == 0x80 && b3 == 0x3F);
  if(isf32){
    mv[j] = (((const float*)mraw)[j] != 0.0f) ? 1 : 0;
  } else if((b1 | b2 | b3) != 0){
    mv[j] = mraw[j] ? 1 : 0;
  } else {
    mv[j] = (((const int*)mraw)[j] != 0) ? 1 : 0;
  }
}

__device__ __forceinline__ void cvt8v(float4 u, float4 v, bf16x8& h, bf16x8& l){
  float buf[8] = {u.x, u.y, u.z, u.w, v.x, v.y, v.z, v.w};
  #pragma unroll
  for(int i = 0; i < 8; i++){
    float f = buf[i];
    __bf16 hi = (__bf16)f;
    h[i] = hi;
    l[i] = (__bf16)(f - (float)hi);
  }
}

__global__ __launch_bounds__(256) void score_mfma(const float* __restrict__ V,
                                                  const float* __restrict__ T,
                                                  const float* __restrict__ invv,
                                                  const float* __restrict__ invt,
                                                  const int* __restrict__ mv,
                                                  unsigned* __restrict__ skey){
  __shared__ __align__(16) char lds[49152];
  __bf16* Ah = (__bf16*)lds;
  __bf16* Al = (__bf16*)(lds + 8192);
  __bf16* Bh = (__bf16*)(lds + 16384);
  __bf16* Bl = (__bf16*)(lds + 32768);
  int tid = threadIdx.x;
  int l = tid & 63, wid = tid >> 6;
  int wr = wid >> 1, n0 = (wid & 1) * 64;
  int vbase = blockIdx.y * 64, tbase = blockIdx.x * 128;
  int arow = tid >> 2;
  int brow = tid >> 1;
  const float* aptr = V + (size_t)(vbase + arow) * DK + (tid & 3) * 16;
  const float* bptr = T + (size_t)(tbase + brow) * DK + (tid & 1) * 32;
  f32x4 acc[2][4];
  #pragma unroll
  for(int i = 0; i < 2; i++)
    #pragma unroll
    for(int j = 0; j < 4; j++) acc[i][j] = (f32x4){0.f, 0.f, 0.f, 0.f};
  float4 fa[4], fb[8];
  #pragma unroll
  for(int c = 0; c < 4; c++) fa[c] = *(const float4*)(aptr + 4*c);
  #pragma unroll
  for(int c = 0; c < 8; c++) fb[c] = *(const float4*)(bptr + 4*c);
  int aswz = arow & 7, bswz = brow & 7;
  for(int k0 = 0; k0 < DK; k0 += 64){
    #pragma unroll
    for(int hhalf = 0; hhalf < 2; hhalf++){
      bf16x8 hv, lv; cvt8v(fa[2*hhalf], fa[2*hhalf+1], hv, lv);
      int slot = (tid & 3)*2 + hhalf;
      int off = arow*64 + ((slot ^ aswz) << 3);
      *(bf16x8*)(Ah + off) = hv; *(bf16x8*)(Al + off) = lv;
    }
    #pragma unroll
    for(int c = 0; c < 4; c++){
      bf16x8 hv, lv; cvt8v(fb[2*c], fb[2*c+1], hv, lv);
      int slot = (tid & 1)*4 + c;
      int off = brow*64 + ((slot ^ bswz) << 3);
      *(bf16x8*)(Bh + off) = hv; *(bf16x8*)(Bl + off) = lv;
    }
    __syncthreads();
    if(k0 + 64 < DK){
      #pragma unroll
      for(int c = 0; c < 4; c++) fa[c] = *(const float4*)(aptr + k0 + 64 + 4*c);
      #pragma unroll
      for(int c = 0; c < 8; c++) fb[c] = *(const float4*)(bptr + k0 + 64 + 4*c);
    }
    #pragma unroll
    for(int kc = 0; kc < 2; kc++){
      bf16x8 ah[2], al[2], bh[4], bl[4];
      int sa = kc*4 + (l >> 4);
      #pragma unroll
      for(int fm = 0; fm < 2; fm++){
        int ra = wr*32 + fm*16 + (l & 15);
        int oa = ra*64 + ((sa ^ (ra & 7)) << 3);
        ah[fm] = *(bf16x8*)(Ah + oa);
        al[fm] = *(bf16x8*)(Al + oa);
      }
      #pragma unroll
      for(int fn = 0; fn < 4; fn++){
        int rb = n0 + fn*16 + (l & 15);
        int ob = rb*64 + ((sa ^ (rb & 7)) << 3);
        bh[fn] = *(bf16x8*)(Bh + ob);
        bl[fn] = *(bf16x8*)(Bl + ob);
      }
      #pragma unroll
      for(int fm = 0; fm < 2; fm++)
        #pragma unroll
        for(int fn = 0; fn < 4; fn++){
          acc[fm][fn] = __builtin_amdgcn_mfma_f32_16x16x32_bf16(ah[fm], bh[fn], acc[fm][fn], 0, 0, 0);
          acc[fm][fn] = __builtin_amdgcn_mfma_f32_16x16x32_bf16(al[fm], bh[fn], acc[fm][fn], 0, 0, 0);
          acc[fm][fn] = __builtin_amdgcn_mfma_f32_16x16x32_bf16(ah[fm], bl[fn], acc[fm][fn], 0, 0, 0);
        }
    }
    __syncthreads();
  }
  float* red = (float*)lds;
  float itc[4];
  #pragma unroll
  for(int fn = 0; fn < 4; fn++){
    int col = tbase + n0 + fn*16 + (l & 15);
    itc[fn] = (mv[col] != 0) ? invt[col] : 0.0f;
  }
  #pragma unroll
  for(int fm = 0; fm < 2; fm++){
    float rm[4];
    #pragma unroll
    for(int e = 0; e < 4; e++){
      int grow = vbase + wr*32 + fm*16 + ((l >> 4) << 2) + e;
      float ivv = invv[grow];
      float mx =     acc[fm][0][e] * itc[0];
      mx = fmaxf(mx, acc[fm][1][e] * itc[1]);
      mx = fmaxf(mx, acc[fm][2][e] * itc[2]);
      mx = fmaxf(mx, acc[fm][3][e] * itc[3]);
      rm[e] = mx * ivv;
    }
    #pragma unroll
    for(int d = 1; d < 16; d <<= 1){
      #pragma unroll
      for(int e = 0; e < 4; e++) rm[e] = fmaxf(rm[e], __shfl_xor(rm[e], d, 16));
    }
    if((l & 15) == 0){
      #pragma unroll
      for(int e = 0; e < 4; e++){
        int rl = wr*32 + fm*16 + ((l >> 4) << 2) + e;
        red[(wid & 1)*64 + rl] = rm[e];
      }
    }
  }
  __syncthreads();
  if(tid < 64){
    float m = fmaxf(red[tid], red[64 + tid]);
    atomicMax(skey + vbase + tid, fkey(m));
  }
}

__global__ __launch_bounds__(256) void scos_gemm(const float* __restrict__ V,
                                                 const int* __restrict__ uniq,
                                                 const float* __restrict__ invv,
                                                 float* __restrict__ scos,
                                                 int U){
  __shared__ __align__(16) float As[32*LDT];
  __shared__ __align__(16) float Bs[32*LDT];
  int tid = threadIdx.x;
  int tx = tid & 15, ty = tid >> 4;
  int ubase = blockIdx.y * 64, ibase = blockIdx.x * 64;
  int r0 = tid >> 3, r1 = r0 + 32;
  int kc = (tid & 7) << 2;
  int g0 = ubase + r0, g1 = ubase + r1;
  int arow0 = (g0 < U) ? uniq[g0] : 0;
  int arow1 = (g1 < U) ? uniq[g1] : 0;
  float acc[4][4] = {};
  for(int k0 = 0; k0 < DK; k0 += 32){
    __syncthreads();
    float4 a0 = *(const float4*)(V + (size_t)arow0*DK + k0 + kc);
    float4 a1 = *(const float4*)(V + (size_t)arow1*DK + k0 + kc);
    float4 b0 = *(const float4*)(V + (size_t)(ibase + r0)*DK + k0 + kc);
    float4 b1 = *(const float4*)(V + (size_t)(ibase + r1)*DK + k0 + kc);
    As[(kc+0)*LDT + r0] = a0.x; As[(kc+1)*LDT + r0] = a0.y; As[(kc+2)*LDT + r0] = a0.z; As[(kc+3)*LDT + r0] = a0.w;
    As[(kc+0)*LDT + r1] = a1.x; As[(kc+1)*LDT + r1] = a1.y; As[(kc+2)*LDT + r1] = a1.z; As[(kc+3)*LDT + r1] = a1.w;
    Bs[(kc+0)*LDT + r0] = b0.x; Bs[(kc+1)*LDT + r0] = b0.y; Bs[(kc+2)*LDT + r0] = b0.z; Bs[(kc+3)*LDT + r0] = b0.w;
    Bs[(kc+0)*LDT + r1] = b1.x; Bs[(kc+1)*LDT + r1] = b1.y; Bs[(kc+2)*LDT + r1] = b1.z; Bs[(kc+3)*LDT + r1] = b1.w;
    __syncthreads();
    #pragma unroll
    for(int k = 0; k < 32; k++){
      float4 a4 = *(const float4*)(As + k*LDT + ty*4);
      float4 b4 = *(const float4*)(Bs + k*LDT + tx*4);
      acc[0][0] += a4.x*b4.x; acc[0][1] += a4.x*b4.y; acc[0][2] += a4.x*b4.z; acc[0][3] += a4.x*b4.w;
      acc[1][0] += a4.y*b4.x; acc[1][1] += a4.y*b4.y; acc[1][2] += a4.y*b4.z; acc[1][3] += a4.y*b4.w;
      acc[2][0] += a4.z*b4.x; acc[2][1] += a4.z*b4.y; acc[2][2] += a4.z*b4.z; acc[2][3] += a4.z*b4.w;
      acc[3][0] += a4.w*b4.x; acc[3][1] += a4.w*b4.y; acc[3][2] += a4.w*b4.z; acc[3][3] += a4.w*b4.w;
    }
  }
  #pragma unroll
  for(int a = 0; a < 4; a++){
    int gu = ubase + ty*4 + a;
    if(gu < U){
      float su = invv[uniq[gu]];
      #pragma unroll
      for(int b = 0; b < 4; b++){
        int i = ibase + tx*4 + b;
        scos[(size_t)gu*NV + i] = acc[a][b] * su * invv[i];
      }
    }
  }
}

// ================= launch =================
extern "C" void kernel_launch(void* const* d_in, const int* in_sizes, int n_in,
                              void* d_out, int out_size, void* d_ws, size_t ws_size,
                              hipStream_t stream){
  const float* V = (const float*)d_in[0];
  const float* T = (const float*)d_in[1];
  const unsigned char* mraw = (const unsigned char*)d_in[2];
  float* out = (float*)d_out;
  int U = out_size / DK;

  // workspace layout (byte offsets, 256-aligned)
  char* W = (char*)d_ws;
  float*    invv  = (float*)W;                  // 576 f
  float*    invt  = (float*)(W + 2560);         // 8192 f
  unsigned* skeyx = (unsigned*)(W + 35584);     // 576 u (exact verified max)
  int*      uniq  = (int*)(W + 38144);          // 576 i
  int*      ucnt  = (int*)(W + 40448);
  unsigned* skey  = (unsigned*)(W + 40704);     // 576 u (approx max / fallback)
  int*      mv    = (int*)(W + 43264);          // 8192 i
  float*    G     = (float*)(W + 76032);        // 576*576 f (also fallback scos)
  __bf16*   Vh    = (__bf16*)(W + 1403136);     // 576*4096 bf16
  __bf16*   Vl    = (__bf16*)(W + 6121728);     // 576*4096 bf16
  float*    cosm  = (float*)(W + 10840320);     // 576*8192 f
  __bf16*   Th    = (__bf16*)(W + 29714688);    // 8192*4096 bf16
  // worklist overlaps Th's region: Th is dead after score_gram, collect runs after.
  int*      wcnt  = (int*)(W + 29714688);
  int2*     wl    = (int2*)(W + 29714944);
  const size_t MAIN_NEED = 96823552;

  if(ws_size >= MAIN_NEED){
    prep_all<<<NT + NV + 32, 256, 0, stream>>>(V, T, mraw, Vh, Vl, Th, invv, invt, mv,
                                               skey, skeyx, wcnt);
    score_gram<<<576 + 81, 256, 0, stream>>>(Vh, Vl, Th, invv, invt, mv, cosm, skey, G);
    collect<<<dim3(NV, 4), 256, 0, stream>>>(cosm, skey, wl, wcnt);
    verify<<<1024, 256, 0, stream>>>(wl, wcnt, V, T, invv, invt, mv, skeyx);
    select_kernel<<<1, 512, 0, stream>>>(skeyx, uniq, ucnt);
    if(U > 0){
      topk_out_kernel<<<U, 256, 0, stream>>>(G, uniq, 1, V, out, U);
    }
  } else {
    hipMemsetAsync(skey, 0, NV*sizeof(unsigned), stream);
    mask_expand<<<(NT + 255)/256, 256, 0, stream>>>(mraw, mv);
    rownorm_kernel<<<NV, 256, 0, stream>>>(V, invv);
    rownorm_kernel<<<NT, 256, 0, stream>>>(T, invt);
    score_mfma<<<dim3(NT/128, NV/64), 256, 0, stream>>>(V, T, invv, invt, mv, skey);
    select_kernel<<<1, 512, 0, stream>>>(skey, uniq, ucnt);
    if(U > 0){
      scos_gemm<<<dim3(NV/64, (U + 63)/64), 256, 0, stream>>>(V, uniq, invv, G, U);
      topk_out_kernel<<<U, 256, 0, stream>>>(G, uniq, 0, V, out, U);
    }
  }
}